// Round 6
// baseline (169.871 us; speedup 1.0000x reference)
//
#include <hip/hip_runtime.h>
#include <hip/hip_bf16.h>

// Round 10 (3rd submit; r4/r5 benches were GPUAcquisitionTimeouts, never ran).
// = r9 (conflict-free layouts, verified 0 bank conflicts) + intra-block
// key-split to double occupancy.
// r9 post-mortem: no pipe saturated (MFMA 28%, VALU 45%, HBM 27%, LDS ~50%)
// -> latency-bound at 4 waves/SIMD, hard-capped by grid (512 blk x 8 waves).
// Fix: 1024-thread blocks, 16 waves; wave-group 0 (w<8) does keys [0,1024),
// group 1 does [1024,2048) for the same 128-query tile -> 8 waves/SIMD.
// Fixed-base softmax (no max) makes the combine LINEAR: O=(O0+O1)/(l0+l1),
// done in-LDS at the end (conflict-free f32x4 overlay), no workspace.
// LDS: 2 groups x dbuf K/V (64KB) + Em (8KB) = 72KB -> 2 blocks/CU = 144KB.
// Everything else identical to r9: conflict-free subtiled LDS layouts,
// reg prefetch, 1 barrier/tile, mask in QK C-init, scale folded into Q.

typedef __attribute__((ext_vector_type(8))) short bf16x8;
typedef __attribute__((ext_vector_type(4))) short bf16x4;
typedef __attribute__((ext_vector_type(4))) float f32x4;

#define B_ 2
#define S_ 2048
#define H_ 16
#define D_ 64
#define BQ 128
#define BK 64
#define NSP 2                  // key-split groups per block
#define NT (S_ / BK)
#define NTH (NT / NSP)         // 16 tiles per group
#define ROWSZ (H_ * D_)        // 1024 floats between s rows

#define LOG2E  1.44269504088896340736f
#define SCALE2 (0.125f * LOG2E)

__device__ __forceinline__ unsigned pack2(float a, float b) {
    union { __hip_bfloat162 h; unsigned u; } x;
    x.h = __float22bfloat162_rn(make_float2(a, b));   // v_cvt_pk_bf16_f32
    return x.u;
}

__device__ __forceinline__ float fexp2(float x) {
#if __has_builtin(__builtin_amdgcn_exp2f)
    return __builtin_amdgcn_exp2f(x);
#else
    return __expf(x * 0.69314718055994531f);
#endif
}

__device__ __forceinline__ f32x4 mfma16(bf16x4 a, bf16x4 b, f32x4 c) {
#if __has_builtin(__builtin_amdgcn_mfma_f32_16x16x16bf16_1k)
    return __builtin_amdgcn_mfma_f32_16x16x16bf16_1k(a, b, c, 0, 0, 0);
#else
    bf16x8 a8 = {a[0], a[1], a[2], a[3], 0, 0, 0, 0};
    bf16x8 b8 = {b[0], b[1], b[2], b[3], 0, 0, 0, 0};
    return __builtin_amdgcn_mfma_f32_16x16x32_bf16(a8, b8, c, 0, 0, 0);
#endif
}

__global__ __launch_bounds__(1024, 8)
void fattn_kernel(const float* __restrict__ qg,
                  const float* __restrict__ kg,
                  const float* __restrict__ vg,
                  const float* __restrict__ maskg,
                  float* __restrict__ outg)
{
    __shared__ __attribute__((aligned(16))) ushort Ks[NSP][2][4096];
    __shared__ __attribute__((aligned(16))) ushort Vt[NSP][2][4096];
    __shared__ __attribute__((aligned(16))) float  Em[S_];   // mask * log2e

    const int qt = blockIdx.x, h = blockIdx.y, b = blockIdx.z;
    const int tid = threadIdx.x;
    const int w = tid >> 6, lane = tid & 63, g = lane >> 4, l15 = lane & 15;
    const int sp = w >> 3, wl = w & 7, t512 = tid & 511;

    // ---- stage pre-scaled mask to LDS (once; 512 threads cover S_) ----
    if (tid < 512) {
        float4 mv = *(const float4*)(maskg + (size_t)b * S_ + tid * 4);
        *(float4*)&Em[tid * 4] = make_float4(mv.x * LOG2E, mv.y * LOG2E,
                                             mv.z * LOG2E, mv.w * LOG2E);
    }

    // ---- Q fragment (B-operand, x32), scale folded in ----
    const int qrow = qt * BQ + wl * 16 + l15;
    const float* qp = qg + (size_t)(b * S_ + qrow) * ROWSZ + h * D_;
    bf16x8 qf[2];
#pragma unroll
    for (int half = 0; half < 2; ++half) {
        float4 f0 = *(const float4*)(qp + half * 32 + g * 8);
        float4 f1 = *(const float4*)(qp + half * 32 + g * 8 + 4);
        union { bf16x8 v; uint4 u; } x;
        x.u = make_uint4(pack2(f0.x * SCALE2, f0.y * SCALE2),
                         pack2(f0.z * SCALE2, f0.w * SCALE2),
                         pack2(f1.x * SCALE2, f1.y * SCALE2),
                         pack2(f1.z * SCALE2, f1.w * SCALE2));
        qf[half] = x.v;
    }

    // ---- staging maps (within this wave-group's 512 threads) ----
    const int skey = t512 >> 4;           // 0..31 (and +32 second pass)
    const int sd   = (t512 & 15) * 4;     // K d-offset (floats)
    const int kw0 = (skey >> 4) * 1024
                  + ((sd >> 3) + ((skey >> 3) & 1) * 8) * 64
                  + (((skey & 7) ^ (sd >> 3)) << 3) + (sd & 7);
    const int kw1 = kw0 + 2048;           // keys +32 -> t+2
    const int vwA = ((wl >> 1) * 4 + (lane >> 4)) * 256
                  + ((2 * wl) & 3) * 64 + (lane & 15) * 4;
    const int vwB = vwA + 64;

    // group-local K/V base: this group's half of the key range
    const size_t kvbase = (size_t)b * S_ * ROWSZ + h * D_
                        + (size_t)sp * (S_ / NSP) * ROWSZ;
    const float* kgs = kg + kvbase;
    const float* vgs = vg + kvbase;

    float4 kpre0, kpre1;
    float  vpre[8];
    auto prefetch = [&](int ktl) {
        const float* kb = kgs + (size_t)ktl * BK * ROWSZ;
        kpre0 = *(const float4*)(kb + (size_t)skey * ROWSZ + sd);
        kpre1 = *(const float4*)(kb + (size_t)(skey + 32) * ROWSZ + sd);
        const float* vb = vgs + (size_t)ktl * BK * ROWSZ + lane;
#pragma unroll
        for (int i = 0; i < 8; ++i) vpre[i] = vb[(size_t)(wl * 8 + i) * ROWSZ];
    };
    auto stage = [&](int buf) {
        *(uint2*)&Ks[sp][buf][kw0] =
            make_uint2(pack2(kpre0.x, kpre0.y), pack2(kpre0.z, kpre0.w));
        *(uint2*)&Ks[sp][buf][kw1] =
            make_uint2(pack2(kpre1.x, kpre1.y), pack2(kpre1.z, kpre1.w));
        *(uint2*)&Vt[sp][buf][vwA] =
            make_uint2(pack2(vpre[0], vpre[1]), pack2(vpre[2], vpre[3]));
        *(uint2*)&Vt[sp][buf][vwB] =
            make_uint2(pack2(vpre[4], vpre[5]), pack2(vpre[6], vpre[7]));
    };

    float l_r = 0.0f;                   // per-lane (q=l15) partial denominator
    f32x4 o_acc[4];
#pragma unroll
    for (int t = 0; t < 4; ++t) o_acc[t] = (f32x4){0.f, 0.f, 0.f, 0.f};

    prefetch(0);
    stage(0);
    __syncthreads();                    // also covers Em staging

    // ---- read bases (thread-constant; reads at immediate offsets) ----
    const int krd0 = (g + (l15 >> 3) * 8) * 64 + (((l15 & 7) ^ g) << 3);
    const int krd1 = (g + 4 + (l15 >> 3) * 8) * 64 + (((l15 & 7) ^ (g + 4)) << 3);
    const int vrd = g * 64 + l15 * 4;

    for (int ktl = 0; ktl < NTH; ++ktl) {
        const int cur = ktl & 1;
        if (ktl + 1 < NTH) prefetch(ktl + 1);  // loads in flight across compute

        // ---- St = K Q^T + mask (C-init) : St[key][q=l15] ----
        const ushort* ks = Ks[sp][cur];
        float sv[4][4];
#pragma unroll
        for (int t = 0; t < 4; ++t) {
            f32x4 acc = *(const f32x4*)&Em[sp * (S_ / NSP) + ktl * BK
                                           + t * 16 + g * 4];  // bcast
            bf16x8 kf0 = *(const bf16x8*)&ks[t * 1024 + krd0];
            bf16x8 kf1 = *(const bf16x8*)&ks[t * 1024 + krd1];
            acc = __builtin_amdgcn_mfma_f32_16x16x32_bf16(kf0, qf[0], acc, 0, 0, 0);
            acc = __builtin_amdgcn_mfma_f32_16x16x32_bf16(kf1, qf[1], acc, 0, 0, 0);
            sv[t][0] = acc[0]; sv[t][1] = acc[1]; sv[t][2] = acc[2]; sv[t][3] = acc[3];
        }

        // ---- fixed-base softmax: p = exp2(s); l += sum ----
        float rs = 0.f;
#pragma unroll
        for (int t = 0; t < 4; ++t)
#pragma unroll
            for (int r = 0; r < 4; ++r) {
                float p = fexp2(sv[t][r]);
                sv[t][r] = p;
                rs += p;
            }
        l_r += rs;

        // ---- P^T fragments direct from regs ----
        bf16x4 pf[4];
#pragma unroll
        for (int c = 0; c < 4; ++c) {
            union { bf16x4 v; uint2 u; } x;
            x.u = make_uint2(pack2(sv[c][0], sv[c][1]), pack2(sv[c][2], sv[c][3]));
            pf[c] = x.v;
        }

        // ---- O^T += V^T P^T : conflict-free b64 reads, 4 acc chains ----
        const ushort* vt = Vt[sp][cur];
#pragma unroll
        for (int c = 0; c < 4; ++c)
#pragma unroll
            for (int t2 = 0; t2 < 4; ++t2) {
                bf16x4 vf = *(const bf16x4*)&vt[(c * 4 + t2) * 256 + vrd];
                o_acc[t2] = mfma16(vf, pf[c], o_acc[t2]);
            }

        if (ktl + 1 < NTH) stage(cur ^ 1);  // vmcnt drain lands post-compute
        __syncthreads();                    // single barrier per tile
    }
    // final loop iteration ended with __syncthreads(): all K/V reads done.

    // ---- combine the two key-split groups (linear: fixed-base softmax) ----
    // overlay: o-partials as lane-contiguous f32x4 planes (conflict-free)
    f32x4* ovl = (f32x4*)&Ks[0][0][0];        // 4 planes x 512 x 16B = 32KB
    float* lvl = (float*)&Vt[0][0][0];        // 512 x 4B
    if (sp == 1) {
#pragma unroll
        for (int t2 = 0; t2 < 4; ++t2)
            ovl[t2 * 512 + wl * 64 + lane] = o_acc[t2];
        lvl[wl * 64 + lane] = l_r;
    }
    __syncthreads();
    if (sp == 0) {
        l_r += lvl[wl * 64 + lane];
#pragma unroll
        for (int t2 = 0; t2 < 4; ++t2) {
            f32x4 p = ovl[t2 * 512 + wl * 64 + lane];
            o_acc[t2][0] += p[0]; o_acc[t2][1] += p[1];
            o_acc[t2][2] += p[2]; o_acc[t2][3] += p[3];
        }
        l_r += __shfl_xor(l_r, 16);
        l_r += __shfl_xor(l_r, 32);
        const float inv = 1.0f / l_r;
        float* op = outg + (size_t)(b * S_ + qrow) * ROWSZ + h * D_;
#pragma unroll
        for (int t2 = 0; t2 < 4; ++t2)
#pragma unroll
            for (int r = 0; r < 4; ++r)
                op[t2 * 16 + g * 4 + r] = o_acc[t2][r] * inv;
    }
}

extern "C" void kernel_launch(void* const* d_in, const int* in_sizes, int n_in,
                              void* d_out, int out_size, void* d_ws, size_t ws_size,
                              hipStream_t stream) {
    dim3 grid(S_ / BQ, H_, B_);   // (16,16,2) = 512 blocks, 2/CU, 16 waves ea
    fattn_kernel<<<grid, dim3(1024), 0, stream>>>(
        (const float*)d_in[0], (const float*)d_in[1], (const float*)d_in[2],
        (const float*)d_in[3], (float*)d_out);
}